// Round 7
// baseline (766.038 us; speedup 1.0000x reference)
//
#include <hip/hip_runtime.h>

#define NB_ 5      // N_BASIS
#define MD_ 5      // MAX_DELAY
#define CSL 128    // post-neurons per coarse bucket (power of 2)
#define CH  4096   // edges per partition block

// ---------------------------------------------------------------------------
// Build (per launch): two-pass counting sort of edges by POST neuron.
// Record uint2: { a = slotbit | (localslot<<18), b = eid }
//   slotbit(e) = (MD-1-d)*bitstride + n   with pre_idx[e] = d*N + n   (18 bits)
//   localslot  = post & (CSL-1)                                      (7 bits)
// inEdge[] sorted by post; row_ptr[p] = inclusive end of post p's run.
// ---------------------------------------------------------------------------

__global__ __launch_bounds__(256) void repack_kernel(
    const float* __restrict__ decay, const float* __restrict__ cf,
    const float* __restrict__ g,     const float* __restrict__ vth,
    const float* __restrict__ vrst,  const float* __restrict__ nrm,
    const float* __restrict__ tref,  const float* __restrict__ ek,
    const float* __restrict__ am,
    float4* __restrict__ pk, float* __restrict__ v, int N)
{
    int n = blockIdx.x * blockDim.x + threadIdx.x;
    if (n >= N) return;
    pk[3 * n]     = make_float4(decay[n], cf[n], g[n], vth[n]);
    pk[3 * n + 1] = make_float4(vrst[n], nrm[n], tref[n], ek[2 * n]);
    pk[3 * n + 2] = make_float4(ek[2 * n + 1], am[2 * n], am[2 * n + 1], 0.0f);
    v[n] = vrst[n];
}

__global__ __launch_bounds__(256) void coarse_hist_kernel(
    const int* __restrict__ post_idx, int* __restrict__ chist, int E)
{
    __shared__ int cntL[512];
    int t = threadIdx.x;
    cntL[t] = 0; cntL[t + 256] = 0;
    __syncthreads();
    int e0 = blockIdx.x * CH;
    int e1 = min(e0 + CH, E);
    for (int e = e0 + t; e < e1; e += 256)
        atomicAdd(&cntL[post_idx[e] >> 7], 1);
    __syncthreads();
    for (int b = t; b < 512; b += 256)
        if (cntL[b]) atomicAdd(&chist[b], cntL[b]);
}

// 1 block: coarse_base[0]=0, coarse_base[i+1]=incl scan; coarse_ptr[i]=excl
__global__ __launch_bounds__(256) void scan_coarse_kernel(
    const int* __restrict__ chist, int* __restrict__ coarse_base,
    int* __restrict__ coarse_ptr, int NC)
{
    __shared__ int tmp[256];
    int t = threadIdx.x;
    int i0 = 2 * t, i1 = 2 * t + 1;
    int a = (i0 < NC) ? chist[i0] : 0;
    int b = (i1 < NC) ? chist[i1] : 0;
    int s = a + b;
    tmp[t] = s;
    __syncthreads();
    for (int off = 1; off < 256; off <<= 1) {
        int y = (t >= off) ? tmp[t - off] : 0;
        __syncthreads();
        tmp[t] += y;
        __syncthreads();
    }
    int ep = tmp[t] - s;
    if (t == 0) coarse_base[0] = 0;
    if (i0 < NC) { coarse_ptr[i0] = ep;     coarse_base[i0 + 1] = ep + a; }
    if (i1 < NC) { coarse_ptr[i1] = ep + a; coarse_base[i1 + 1] = ep + s; }
}

__global__ __launch_bounds__(256) void partition_kernel(
    const int* __restrict__ pre_idx,
    const int* __restrict__ post_idx,
    int* __restrict__ coarse_ptr,
    uint2* __restrict__ part,
    int E, int N, int bitstride)
{
    __shared__ int cntL[512];
    __shared__ int posL[512];
    int t = threadIdx.x;
    cntL[t] = 0; cntL[t + 256] = 0;
    __syncthreads();
    int e0 = blockIdx.x * CH;
    int e1 = min(e0 + CH, E);
    for (int e = e0 + t; e < e1; e += 256)
        atomicAdd(&cntL[post_idx[e] >> 7], 1);
    __syncthreads();
    for (int b = t; b < 512; b += 256)
        posL[b] = cntL[b] ? atomicAdd(&coarse_ptr[b], cntL[b]) : 0;
    __syncthreads();
    for (int e = e0 + t; e < e1; e += 256) {
        int post = post_idx[e];
        int pre  = pre_idx[e];
        int d = pre / N;
        unsigned slotbit = (unsigned)((MD_ - 1 - d) * bitstride + (pre - d * N));
        int p = atomicAdd(&posL[post >> 7], 1);
        uint2 q;
        q.x = slotbit | ((unsigned)(post & (CSL - 1)) << 18);
        q.y = (unsigned)e;
        part[p] = q;
    }
}

// one block per coarse bucket: LDS counting sort over CSL local post slots
__global__ __launch_bounds__(256) void bucket_sort_kernel(
    const int* __restrict__ coarse_base,
    const uint2* __restrict__ part,
    uint2* __restrict__ inEdge,
    int* __restrict__ row_ptr, int N)
{
    __shared__ int h[CSL];
    __shared__ int sc_[CSL];
    __shared__ int pos_[CSL];
    int c = blockIdx.x, t = threadIdx.x;
    int lo = coarse_base[c], hi = coarse_base[c + 1];
    if (t < CSL) h[t] = 0;
    __syncthreads();
    for (int i = lo + t; i < hi; i += 256)
        atomicAdd(&h[part[i].x >> 18], 1);
    __syncthreads();
    if (t < CSL) sc_[t] = h[t];
    __syncthreads();
    for (int off = 1; off < CSL; off <<= 1) {
        int y = 0;
        if (t < CSL && t >= off) y = sc_[t - off];
        __syncthreads();
        if (t < CSL && t >= off) sc_[t] += y;
        __syncthreads();
    }
    if (t < CSL) {
        pos_[t] = lo + sc_[t] - h[t];          // exclusive start
        int gp = c * CSL + t;
        if (gp < N) row_ptr[gp] = lo + sc_[t]; // inclusive end
    }
    __syncthreads();
    for (int i = lo + t; i < hi; i += 256) {
        uint2 q = part[i];
        int dst = atomicAdd(&pos_[q.x >> 18], 1);
        inEdge[dst] = q;
    }
}

// ---------------------------------------------------------------------------
// Fused per-step kernel: gated pull-model edge gather + neuron update
// ---------------------------------------------------------------------------

__global__ __launch_bounds__(256) void step_kernel(
    const float* __restrict__ x_t,        // ext_input + t*n5
    float*       __restrict__ psc,        // n5
    const float* __restrict__ sd,         // syn_decay n5
    const float* __restrict__ pi,         // psc_initial n5
    const float4* __restrict__ pk,        // {decay,cf,g,vth}{vrst,nrm,tref,ek0}{ek1,am0,am1,_}
    float* __restrict__ v,
    float* __restrict__ r,
    float* __restrict__ asc,              // (N,2)
    const int* __restrict__ scnt_t,       // scnt + t  (5-slot window)
    int*       __restrict__ scnt_new,     // scnt + t + MD
    const unsigned* __restrict__ zbits_t, // zbits + t*words32 (5-row window)
    const unsigned* __restrict__ zrow_prev,
    unsigned*       __restrict__ zrow_new,
    const int*   __restrict__ row_ptr,    // by-post CSR (inclusive ends)
    const uint2* __restrict__ inEdge,
    const float* __restrict__ weights,
    const float* __restrict__ edge_basis,
    float* __restrict__ out_t,
    int N, int wwords)
{
    extern __shared__ unsigned zw[];      // wwords u32 (staged bit window)
    __shared__ int scw_s;
    int t = threadIdx.x;
    int n = blockIdx.x * blockDim.x + t;

    if (t == 0)
        scw_s = scnt_t[0] + scnt_t[1] + scnt_t[2] + scnt_t[3] + scnt_t[4];
    __syncthreads();
    int scw = scw_s;

    if (scw > 0) {
        for (int i = t; i < wwords; i += blockDim.x) zw[i] = zbits_t[i];
        __syncthreads();
    }

    bool has = (n < N);
    float z = 0.0f;
    if (has) {
        // ---- pull-model recurrent input (registers, no atomics) ----------
        float ir0 = 0.f, ir1 = 0.f, ir2 = 0.f, ir3 = 0.f, ir4 = 0.f;
        if (scw > 0) {
            int start = n ? row_ptr[n - 1] : 0;
            int end   = row_ptr[n];
            for (int i = start; i < end; ++i) {
                uint2 q = inEdge[i];
                unsigned sb = q.x & 0x3FFFFu;
                if ((zw[sb >> 5] >> (sb & 31)) & 1u) {
                    int e = (int)q.y;
                    float w = weights[e];
                    const float* bs = edge_basis + (size_t)e * NB_;
                    ir0 += w * bs[0];
                    ir1 += w * bs[1];
                    ir2 += w * bs[2];
                    ir3 += w * bs[3];
                    ir4 += w * bs[4];
                }
            }
        }

        // ---- psc recurrence + input current (k ascending, ref order) -----
        const float* xp  = x_t + (size_t)n * NB_;
        float*       pp  = psc + (size_t)n * NB_;
        const float* sdp = sd  + (size_t)n * NB_;
        const float* pip = pi  + (size_t)n * NB_;
        float ic = 0.0f, pv;
        pv = pp[0] * sdp[0] + (ir0 + xp[0]) * pip[0]; pp[0] = pv; ic += pv;
        pv = pp[1] * sdp[1] + (ir1 + xp[1]) * pip[1]; pp[1] = pv; ic += pv;
        pv = pp[2] * sdp[2] + (ir2 + xp[2]) * pip[2]; pp[2] = pv; ic += pv;
        pv = pp[3] * sdp[3] + (ir3 + xp[3]) * pip[3]; pp[3] = pv; ic += pv;
        pv = pp[4] * sdp[4] + (ir4 + xp[4]) * pip[4]; pp[4] = pv; ic += pv;

        float4 P0 = pk[3 * n], P1 = pk[3 * n + 1], P2 = pk[3 * n + 2];

        unsigned pwd = zrow_prev[n >> 5];
        float pz = ((pwd >> (n & 31)) & 1u) ? 1.0f : 0.0f;

        float a0 = P1.w * asc[2 * n]     + pz * P2.y;
        float a1 = P2.x * asc[2 * n + 1] + pz * P2.z;
        asc[2 * n]     = a0;
        asc[2 * n + 1] = a1;

        float c1 = ic + (a0 + a1) + P0.z;
        float nv = P0.x * v[n] + P0.y * c1;
        if (pz > 0.5f) nv = P1.x;

        float vsc = (nv - P0.w) / P1.y;
        z = (vsc > 0.0f) ? 1.0f : 0.0f;
        float rr = r[n];
        if (rr > 0.0f) z = 0.0f;

        r[n] = fmaxf(rr + z * P1.z - 1.0f, 0.0f);   // DT = 1.0
        v[n] = nv;
        out_t[n] = z;
    }

    // bit-pack this step's spikes: one u64 store per wave
    unsigned long long m = __ballot(z != 0.0f);
    int gtid = blockIdx.x * blockDim.x + t;
    int wv = gtid >> 6;
    if ((t & 63) == 0 && (wv << 6) < N) {
        *(unsigned long long*)(zrow_new + (wv << 1)) = m;
        if (m) atomicAdd(scnt_new, __popcll(m));
    }
}

// ---------------------------------------------------------------------------
// Launcher
// ---------------------------------------------------------------------------

extern "C" void kernel_launch(void* const* d_in, const int* in_sizes, int n_in,
                              void* d_out, int out_size, void* d_ws, size_t ws_size,
                              hipStream_t stream)
{
    const float* weights        = (const float*)d_in[0];
    const float* edge_basis     = (const float*)d_in[1];
    const float* ext_input      = (const float*)d_in[2];
    const float* decay          = (const float*)d_in[3];
    const float* current_factor = (const float*)d_in[4];
    const float* gathered_g     = (const float*)d_in[5];
    const float* v_th           = (const float*)d_in[6];
    const float* v_reset        = (const float*)d_in[7];
    const float* normalizer     = (const float*)d_in[8];
    const float* t_ref          = (const float*)d_in[9];
    const float* exp_dt_k       = (const float*)d_in[10];
    const float* asc_amps       = (const float*)d_in[11];
    const float* syn_decay      = (const float*)d_in[12];
    const float* psc_initial    = (const float*)d_in[13];
    const int*   pre_idx        = (const int*)d_in[14];
    const int*   post_idx       = (const int*)d_in[15];

    const int E  = in_sizes[0];
    const int N  = in_sizes[3];
    const int n5 = N * NB_;
    const int T  = in_sizes[2] / n5;            // B = 1

    const int words64   = (N + 63) / 64;        // 782
    const int words32   = words64 * 2;          // 1564
    const int bitstride = words32 * 32;         // 50048
    const int wwords    = words32 * MD_;        // 7820 (31.3 KB window)
    const int NC        = (N + CSL - 1) / CSL;  // 391 coarse post-buckets

    float* out = (float*)d_out;

    // ---- workspace layout --------------------------------------------------
    char* wsb = (char*)d_ws;
    size_t o = 0;
    // zero group:
    int*   chist = (int*)(wsb + o);   o += 512 * 4;
    float* psc   = (float*)(wsb + o); o += (size_t)n5 * 4;
    float* r     = (float*)(wsb + o); o += (size_t)N * 4;
    float* asc   = (float*)(wsb + o); o += (size_t)2 * N * 4;
    int*   scnt  = (int*)(wsb + o);   o += (size_t)(T + MD_) * 4;
    o = (o + 15) & ~(size_t)15;
    unsigned* zbits = (unsigned*)(wsb + o);
    size_t zero_bytes = o + (size_t)MD_ * words32 * 4;     // zbits head only
    o += (size_t)(T + MD_) * words32 * 4;
    // non-zeroed:
    o = (o + 15) & ~(size_t)15;
    float*  v           = (float*)(wsb + o);  o += (size_t)N * 4;
    float4* pk          = (float4*)(wsb + o); o += (size_t)N * 12 * 4;
    int*    row_ptr     = (int*)(wsb + o);    o += (size_t)N * 4;
    int*    coarse_base = (int*)(wsb + o);    o += 513 * 4;
    int*    coarse_ptr  = (int*)(wsb + o);    o += 512 * 4;
    o = (o + 15) & ~(size_t)15;
    uint2*  part        = (uint2*)(wsb + o);  o += (size_t)E * 8;
    uint2*  inEdge      = (uint2*)(wsb + o);  o += (size_t)E * 8;

    // ---- build (every launch; graph replays everything) --------------------
    hipMemsetAsync(d_ws, 0, zero_bytes, stream);

    repack_kernel<<<(N + 255) / 256, 256, 0, stream>>>(
        decay, current_factor, gathered_g, v_th, v_reset, normalizer, t_ref,
        exp_dt_k, asc_amps, pk, v, N);

    const int nbe = (E + CH - 1) / CH;   // 489
    coarse_hist_kernel<<<nbe, 256, 0, stream>>>(post_idx, chist, E);
    scan_coarse_kernel<<<1, 256, 0, stream>>>(chist, coarse_base, coarse_ptr, NC);
    partition_kernel<<<nbe, 256, 0, stream>>>(
        pre_idx, post_idx, coarse_ptr, part, E, N, bitstride);
    bucket_sort_kernel<<<NC, 256, 0, stream>>>(coarse_base, part, inEdge, row_ptr, N);

    // ---- time loop: ONE fused kernel per step ------------------------------
    const int nblk = (N + 255) / 256;    // 196
    const size_t shmem = (size_t)wwords * 4;
    for (int t = 0; t < T; ++t) {
        step_kernel<<<nblk, 256, shmem, stream>>>(
            ext_input + (size_t)t * n5,
            psc, syn_decay, psc_initial,
            pk, v, r, asc,
            scnt + t, scnt + t + MD_,
            zbits + (size_t)t * words32,
            zbits + (size_t)(t + MD_ - 1) * words32,
            zbits + (size_t)(t + MD_) * words32,
            row_ptr, inEdge, weights, edge_basis,
            out + (size_t)t * N,
            N, wwords);
    }
}